// Round 2
// baseline (3260.159 us; speedup 1.0000x reference)
//
#include <hip/hip_runtime.h>
#include <hip/hip_bf16.h>

#define N0 200000
#define N1 150000
#define N2 120000
#define N3 100000
#define E0 2000000
#define E1 1000000
#define E2 500000
#define ESUB 250000

// ---------------- degree count ----------------
__global__ void k_degree(const int* __restrict__ idx, int n, float* __restrict__ deg, int limit) {
    int i = blockIdx.x * blockDim.x + threadIdx.x;
    if (i < n) {
        int d = idx[i];
        if ((unsigned)d < (unsigned)limit) atomicAdd(&deg[d], 1.0f);
    }
}

// ---------------- scatter rel_emb rows to S_out (src<N1) and S_in (dst) ----------------
__global__ void k_scatter0(const int* __restrict__ typ, const int* __restrict__ src,
                           const int* __restrict__ dst, const float* __restrict__ rel_emb,
                           float* __restrict__ S_out, float* __restrict__ S_in) {
    long long i = (long long)blockIdx.x * blockDim.x + threadIdx.x;
    if (i >= (long long)E0 * 32) return;
    int e = (int)(i >> 5);
    int d = (int)(i & 31);
    float v = rel_emb[typ[e] * 32 + d];
    int s = src[e];
    if (s < N1) atomicAdd(&S_out[s * 32 + d], v);
    atomicAdd(&S_in[dst[e] * 32 + d], v);
}

// ---------------- combine: x = [ (S_out/deg)@W_out+b_out , (S_in/deg)@W_in+b_in ] * rsqrt(deg1_o) ----------------
__global__ void k_combine(const float* __restrict__ S_out, const float* __restrict__ S_in,
                          const float* __restrict__ deg_src, const float* __restrict__ deg_dst,
                          const float* __restrict__ deg1_o,
                          const float* __restrict__ W_out, const float* __restrict__ b_out,
                          const float* __restrict__ W_in, const float* __restrict__ b_in,
                          float* __restrict__ h1) {
    int i = blockIdx.x * blockDim.x + threadIdx.x;
    if (i >= N1 * 64) return;
    int n = i >> 6, j = i & 63;
    const float* S;
    const float* W;
    float b, deg;
    int col;
    if (j < 32) { S = S_out + n * 32; W = W_out; b = b_out[j];      deg = deg_src[n]; col = j; }
    else        { S = S_in  + n * 32; W = W_in;  b = b_in[j - 32];  deg = deg_dst[n]; col = j - 32; }
    float res = 0.0f;
    if (deg > 0.5f) {
        float acc = 0.0f;
#pragma unroll
        for (int k = 0; k < 32; k++) acc += S[k] * W[k * 32 + col];
        res = acc / deg + b;
    }
    h1[i] = res * rsqrtf(fmaxf(deg1_o[n], 1.0f));
}

// ---------------- scatter1: agg1[dst] += h1[src] (64-dim) ----------------
__global__ void k_scatter1(const int* __restrict__ src, const int* __restrict__ dst,
                           const float* __restrict__ h1, float* __restrict__ agg1) {
    long long i = (long long)blockIdx.x * blockDim.x + threadIdx.x;
    if (i >= (long long)E1 * 64) return;
    int e = (int)(i >> 6), d = (int)(i & 63);
    atomicAdd(&agg1[dst[e] * 64 + d], h1[src[e] * 64 + d]);
}

// ---------------- conv1: h2 = relu((agg1*rsqrt(deg1_i)) @ W1 + b1) * rsqrt(deg2_o) ----------------
__global__ __launch_bounds__(256) void k_conv1(const float* __restrict__ agg1,
                                               const float* __restrict__ deg1_i,
                                               const float* __restrict__ deg2_o,
                                               const float* __restrict__ W1, const float* __restrict__ b1,
                                               float* __restrict__ h2) {
    __shared__ float row[8][64];
    int base = blockIdx.x * 8;
    int tid = threadIdx.x;
    for (int v = tid; v < 512; v += 256) {
        int m = v >> 6, k = v & 63;
        row[m][k] = agg1[(base + m) * 64 + k] * rsqrtf(fmaxf(deg1_i[base + m], 1.0f));
    }
    __syncthreads();
    float acc[8] = {0, 0, 0, 0, 0, 0, 0, 0};
    for (int k = 0; k < 64; k++) {
        float w = W1[k * 256 + tid];
#pragma unroll
        for (int m = 0; m < 8; m++) acc[m] += row[m][k] * w;
    }
    float bb = b1[tid];
#pragma unroll
    for (int m = 0; m < 8; m++) {
        float v = fmaxf(acc[m] + bb, 0.0f) * rsqrtf(fmaxf(deg2_o[base + m], 1.0f));
        h2[(base + m) * 256 + tid] = v;
    }
}

// ---------------- scatter2: agg2[dst] += h2[src] (256-dim) ----------------
__global__ void k_scatter2(const int* __restrict__ src, const int* __restrict__ dst,
                           const float* __restrict__ h2, float* __restrict__ agg2) {
    long long i = (long long)blockIdx.x * blockDim.x + threadIdx.x;
    if (i >= (long long)E2 * 256) return;
    int e = (int)(i >> 8), d = (int)(i & 255);
    atomicAdd(&agg2[dst[e] * 256 + d], h2[src[e] * 256 + d]);
}

// ---------------- conv2 (in-place): x3 = relu((agg2*rsqrt(deg2_i)) @ W2 + b2) ----------------
__global__ __launch_bounds__(256) void k_conv2(float* __restrict__ agg2_x3,
                                               const float* __restrict__ deg2_i,
                                               const float* __restrict__ W2, const float* __restrict__ b2v) {
    __shared__ float row[8][256];
    int base = blockIdx.x * 8;
    int tid = threadIdx.x;
#pragma unroll
    for (int m = 0; m < 8; m++)
        row[m][tid] = agg2_x3[(base + m) * 256 + tid] * rsqrtf(fmaxf(deg2_i[base + m], 1.0f));
    __syncthreads();
    float acc[8] = {0, 0, 0, 0, 0, 0, 0, 0};
    for (int k = 0; k < 256; k++) {
        float w = W2[k * 256 + tid];
#pragma unroll
        for (int m = 0; m < 8; m++) acc[m] += row[m][k] * w;
    }
    float bb = b2v[tid];
#pragma unroll
    for (int m = 0; m < 8; m++)
        agg2_x3[(base + m) * 256 + tid] = fmaxf(acc[m] + bb, 0.0f);
}

// ---------------- final: out = [x3[sub_src], x3[sub_dst]] @ Wfc + bfc ----------------
__global__ __launch_bounds__(256) void k_final(const int* __restrict__ ss, const int* __restrict__ sd,
                                               const float* __restrict__ x3,
                                               const float* __restrict__ Wfc, const float* __restrict__ bfc,
                                               float* __restrict__ out) {
    __shared__ float row[8][512];
    int base = blockIdx.x * 8;
    int tid = threadIdx.x;
#pragma unroll
    for (int m = 0; m < 8; m++) {
        int e = base + m;
        row[m][tid]       = x3[ss[e] * 256 + tid];
        row[m][256 + tid] = x3[sd[e] * 256 + tid];
    }
    __syncthreads();
    float acc[8] = {0, 0, 0, 0, 0, 0, 0, 0};
    for (int k = 0; k < 512; k++) {
        float w = Wfc[k * 256 + tid];
#pragma unroll
        for (int m = 0; m < 8; m++) acc[m] += row[m][k] * w;
    }
    float bb = bfc[tid];
#pragma unroll
    for (int m = 0; m < 8; m++)
        out[(size_t)(base + m) * 256 + tid] = acc[m] + bb;
}

extern "C" void kernel_launch(void* const* d_in, const int* in_sizes, int n_in,
                              void* d_out, int out_size, void* d_ws, size_t ws_size,
                              hipStream_t stream) {
    const int* e0_type = (const int*)d_in[0];
    const int* e0_src  = (const int*)d_in[1];
    const int* e0_dst  = (const int*)d_in[2];
    const int* e1_src  = (const int*)d_in[3];
    const int* e1_dst  = (const int*)d_in[4];
    const int* e2_src  = (const int*)d_in[5];
    const int* e2_dst  = (const int*)d_in[6];
    const int* sub_src = (const int*)d_in[7];
    const int* sub_dst = (const int*)d_in[8];
    const float* rel_emb = (const float*)d_in[9];
    const float* W_out   = (const float*)d_in[10];
    const float* b_out   = (const float*)d_in[11];
    const float* W_in    = (const float*)d_in[12];
    const float* b_in    = (const float*)d_in[13];
    const float* W1      = (const float*)d_in[14];
    const float* b1      = (const float*)d_in[15];
    const float* W2      = (const float*)d_in[16];
    const float* b2v     = (const float*)d_in[17];
    const float* Wfc     = (const float*)d_in[18];
    const float* bfc     = (const float*)d_in[19];
    float* out = (float*)d_out;

    // ---- packed workspace layout (floats), peak ~228 MB ----
    // deg block | P0: [S_out,S_in]/agg1/agg2 (reused) | P0+25.6M: h1.. / h2 region
    float* ws = (float*)d_ws;
    size_t o = 0;
    float* deg0_src = ws + o; o += N1;
    float* deg0_dst = ws + o; o += N1;
    float* deg1_o   = ws + o; o += N1;
    float* deg1_i   = ws + o; o += N2;
    float* deg2_o   = ws + o; o += N2;
    float* deg2_i   = ws + o; o += N3;
    size_t P0 = o;                                  // 790000
    float* S_out = ws + P0;                         // [scatter0, combine)  N1*32
    float* S_in  = ws + P0 + (size_t)N1 * 32;       //                      N1*32
    float* h1    = ws + P0 + (size_t)N1 * 64;       // [combine, scatter1)  N1*64
    float* agg1  = ws + P0;                         // [scatter1, conv1)    N2*64  (reuses S)
    float* agg2  = ws + P0;                         // [scatter2, end)      N3*256 (reuses S/h1/agg1)
    float* h2    = ws + P0 + (size_t)N3 * 256;      // [conv1, scatter2)    N2*256 (above agg2)

    const int BT = 256;

    // zero degrees + S_out/S_in in one go
    hipMemsetAsync(ws, 0, (P0 + (size_t)N1 * 64) * sizeof(float), stream);

    // degrees
    k_degree<<<(E0 + BT - 1) / BT, BT, 0, stream>>>(e0_src, E0, deg0_src, N1);
    k_degree<<<(E0 + BT - 1) / BT, BT, 0, stream>>>(e0_dst, E0, deg0_dst, N1);
    k_degree<<<(E1 + BT - 1) / BT, BT, 0, stream>>>(e1_src, E1, deg1_o, N1);
    k_degree<<<(E1 + BT - 1) / BT, BT, 0, stream>>>(e1_dst, E1, deg1_i, N2);
    k_degree<<<(E2 + BT - 1) / BT, BT, 0, stream>>>(e2_src, E2, deg2_o, N2);
    k_degree<<<(E2 + BT - 1) / BT, BT, 0, stream>>>(e2_dst, E2, deg2_i, N3);

    // layer 0 scatter + combine
    long long t0 = (long long)E0 * 32;
    k_scatter0<<<(int)((t0 + BT - 1) / BT), BT, 0, stream>>>(e0_type, e0_src, e0_dst, rel_emb, S_out, S_in);
    k_combine<<<(N1 * 64 + BT - 1) / BT, BT, 0, stream>>>(S_out, S_in, deg0_src, deg0_dst, deg1_o,
                                                          W_out, b_out, W_in, b_in, h1);

    // conv1 (zero agg1 after combine has consumed S, before scatter1)
    hipMemsetAsync(agg1, 0, (size_t)N2 * 64 * sizeof(float), stream);
    long long t1 = (long long)E1 * 64;
    k_scatter1<<<(int)((t1 + BT - 1) / BT), BT, 0, stream>>>(e1_src, e1_dst, h1, agg1);
    k_conv1<<<N2 / 8, BT, 0, stream>>>(agg1, deg1_i, deg2_o, W1, b1, h2);

    // conv2 (zero agg2 after conv1 has consumed agg1, before scatter2)
    hipMemsetAsync(agg2, 0, (size_t)N3 * 256 * sizeof(float), stream);
    long long t2 = (long long)E2 * 256;
    k_scatter2<<<(int)((t2 + BT - 1) / BT), BT, 0, stream>>>(e2_src, e2_dst, h2, agg2);
    k_conv2<<<N3 / 8, BT, 0, stream>>>(agg2, deg2_i, W2, b2v);

    // final edge MLP
    k_final<<<ESUB / 8, BT, 0, stream>>>(sub_src, sub_dst, agg2, Wfc, bfc, out);
}

// Round 3
// 2010.969 us; speedup vs baseline: 1.6212x; 1.6212x over previous
//
#include <hip/hip_runtime.h>
#include <hip/hip_bf16.h>

#define N0 200000
#define N1 150000
#define N2 120000
#define N3 100000
#define E0 2000000
#define E1 1000000
#define E2 500000
#define ESUB 250000

typedef float f32x4 __attribute__((ext_vector_type(4)));
typedef __bf16 bf16x8 __attribute__((ext_vector_type(8)));

// ---------------- degree count ----------------
__global__ void k_degree(const int* __restrict__ idx, int n, float* __restrict__ deg, int limit) {
    int i = blockIdx.x * blockDim.x + threadIdx.x;
    if (i < n) {
        int d = idx[i];
        if ((unsigned)d < (unsigned)limit) atomicAdd(&deg[d], 1.0f);
    }
}

// ---------------- scatter rel_emb rows to S_out (src<N1) and S_in (dst) ----------------
__global__ void k_scatter0(const int* __restrict__ typ, const int* __restrict__ src,
                           const int* __restrict__ dst, const float* __restrict__ rel_emb,
                           float* __restrict__ S_out, float* __restrict__ S_in) {
    long long i = (long long)blockIdx.x * blockDim.x + threadIdx.x;
    if (i >= (long long)E0 * 32) return;
    int e = (int)(i >> 5);
    int d = (int)(i & 31);
    float v = rel_emb[typ[e] * 32 + d];
    int s = src[e];
    if (s < N1) atomicAdd(&S_out[s * 32 + d], v);
    atomicAdd(&S_in[dst[e] * 32 + d], v);
}

// ---------------- combine ----------------
__global__ void k_combine(const float* __restrict__ S_out, const float* __restrict__ S_in,
                          const float* __restrict__ deg_src, const float* __restrict__ deg_dst,
                          const float* __restrict__ deg1_o,
                          const float* __restrict__ W_out, const float* __restrict__ b_out,
                          const float* __restrict__ W_in, const float* __restrict__ b_in,
                          float* __restrict__ h1) {
    int i = blockIdx.x * blockDim.x + threadIdx.x;
    if (i >= N1 * 64) return;
    int n = i >> 6, j = i & 63;
    const float* S;
    const float* W;
    float b, deg;
    int col;
    if (j < 32) { S = S_out + n * 32; W = W_out; b = b_out[j];      deg = deg_src[n]; col = j; }
    else        { S = S_in  + n * 32; W = W_in;  b = b_in[j - 32];  deg = deg_dst[n]; col = j - 32; }
    float res = 0.0f;
    if (deg > 0.5f) {
        float acc = 0.0f;
#pragma unroll
        for (int k = 0; k < 32; k++) acc += S[k] * W[k * 32 + col];
        res = acc / deg + b;
    }
    h1[i] = res * rsqrtf(fmaxf(deg1_o[n], 1.0f));
}

// ---------------- scatter1: agg1[dst] += h1[src] (64-dim) ----------------
__global__ void k_scatter1(const int* __restrict__ src, const int* __restrict__ dst,
                           const float* __restrict__ h1, float* __restrict__ agg1) {
    long long i = (long long)blockIdx.x * blockDim.x + threadIdx.x;
    if (i >= (long long)E1 * 64) return;
    int e = (int)(i >> 6), d = (int)(i & 63);
    atomicAdd(&agg1[dst[e] * 64 + d], h1[src[e] * 64 + d]);
}

// ---------------- conv1: h2 = relu((agg1*rsqrt(deg1_i)) @ W1 + b1) * rsqrt(deg2_o) ----------------
__global__ __launch_bounds__(256) void k_conv1(const float* __restrict__ agg1,
                                               const float* __restrict__ deg1_i,
                                               const float* __restrict__ deg2_o,
                                               const float* __restrict__ W1, const float* __restrict__ b1,
                                               float* __restrict__ h2) {
    __shared__ float row[8][64];
    int base = blockIdx.x * 8;
    int tid = threadIdx.x;
    for (int v = tid; v < 512; v += 256) {
        int m = v >> 6, k = v & 63;
        row[m][k] = agg1[(base + m) * 64 + k] * rsqrtf(fmaxf(deg1_i[base + m], 1.0f));
    }
    __syncthreads();
    float acc[8] = {0, 0, 0, 0, 0, 0, 0, 0};
    for (int k = 0; k < 64; k++) {
        float w = W1[k * 256 + tid];
#pragma unroll
        for (int m = 0; m < 8; m++) acc[m] += row[m][k] * w;
    }
    float bb = b1[tid];
#pragma unroll
    for (int m = 0; m < 8; m++) {
        float v = fmaxf(acc[m] + bb, 0.0f) * rsqrtf(fmaxf(deg2_o[base + m], 1.0f));
        h2[(base + m) * 256 + tid] = v;
    }
}

// ---------------- scatter2: agg2[dst] += h2[src] (256-dim) ----------------
__global__ void k_scatter2(const int* __restrict__ src, const int* __restrict__ dst,
                           const float* __restrict__ h2, float* __restrict__ agg2) {
    long long i = (long long)blockIdx.x * blockDim.x + threadIdx.x;
    if (i >= (long long)E2 * 256) return;
    int e = (int)(i >> 8), d = (int)(i & 255);
    atomicAdd(&agg2[dst[e] * 256 + d], h2[src[e] * 256 + d]);
}

// ---------------- pack W (K x 256 f32, row-major) into MFMA B-fragment order (bf16) ----------------
// packed[((tn*ksteps + ks)*64 + lane)*8 + j] = W[(ks*32 + (lane>>4)*8 + j)*256 + tn*16 + (lane&15)]
__global__ void k_pack(const float* __restrict__ W, __bf16* __restrict__ Wp, int ksteps) {
    int idx = blockIdx.x * 256 + threadIdx.x;
    int j = idx & 7;
    int lane = (idx >> 3) & 63;
    int rest = idx >> 9;
    int ks = rest % ksteps;
    int tn = rest / ksteps;
    int k = ks * 32 + ((lane >> 4) * 8) + j;
    int n = tn * 16 + (lane & 15);
    Wp[idx] = (__bf16)W[k * 256 + n];
}

// ---------------- conv2 via MFMA: x3b = bf16(relu((agg2*rsqrt(deg2_i)) @ W2 + b2)) ----------------
__global__ __launch_bounds__(256) void k_conv2_mfma(const float* __restrict__ agg2,
                                                    const float* __restrict__ deg2_i,
                                                    const __bf16* __restrict__ W2p,
                                                    const float* __restrict__ b2v,
                                                    __bf16* __restrict__ x3b) {
    __shared__ __bf16 At[64][264];   // +8 pad -> 2-way LDS conflicts only
    int t = threadIdx.x;
    int base = blockIdx.x * 64;
#pragma unroll
    for (int it = 0; it < 16; it++) {
        int c = it * 256 + t;       // 0..4095
        int row = c >> 6;           // 0..63
        int off4 = (c & 63) * 4;    // 0..252
        int rg = base + row; if (rg >= N3) rg = N3 - 1;
        float sc = rsqrtf(fmaxf(deg2_i[rg], 1.0f));
        float4 v = *(const float4*)(agg2 + (size_t)rg * 256 + off4);
        union { __bf16 b[4]; uint2 u; } cv;
        cv.b[0] = (__bf16)(v.x * sc); cv.b[1] = (__bf16)(v.y * sc);
        cv.b[2] = (__bf16)(v.z * sc); cv.b[3] = (__bf16)(v.w * sc);
        *(uint2*)&At[row][off4] = cv.u;
    }
    __syncthreads();
    int wave = t >> 6, lane = t & 63;
    int q = lane >> 4, r16 = lane & 15;
    f32x4 acc[4][4] = {};
    for (int ks = 0; ks < 8; ks++) {
        bf16x8 a[4], b[4];
        int ko = ks * 32 + q * 8;
#pragma unroll
        for (int mt = 0; mt < 4; mt++)
            a[mt] = *(const bf16x8*)&At[mt * 16 + r16][ko];
#pragma unroll
        for (int i = 0; i < 4; i++) {
            int tn = wave * 4 + i;
            b[i] = *(const bf16x8*)&W2p[((size_t)(tn * 8 + ks) * 64 + lane) * 8];
        }
#pragma unroll
        for (int mt = 0; mt < 4; mt++)
#pragma unroll
            for (int i = 0; i < 4; i++)
                acc[mt][i] = __builtin_amdgcn_mfma_f32_16x16x32_bf16(a[mt], b[i], acc[mt][i], 0, 0, 0);
    }
#pragma unroll
    for (int mt = 0; mt < 4; mt++) {
#pragma unroll
        for (int i = 0; i < 4; i++) {
            int col = (wave * 4 + i) * 16 + r16;
            float bb = b2v[col];
#pragma unroll
            for (int rr = 0; rr < 4; rr++) {
                int row = base + mt * 16 + q * 4 + rr;
                if (row < N3)
                    x3b[(size_t)row * 256 + col] = (__bf16)fmaxf(acc[mt][i][rr] + bb, 0.0f);
            }
        }
    }
}

// ---------------- final via MFMA: out = [x3b[ss], x3b[sd]] @ Wfc + bfc ----------------
__global__ __launch_bounds__(256) void k_final_mfma(const int* __restrict__ ss, const int* __restrict__ sd,
                                                    const __bf16* __restrict__ x3b,
                                                    const __bf16* __restrict__ Wp,
                                                    const float* __restrict__ bfc,
                                                    float* __restrict__ out) {
    __shared__ __bf16 At[64][520];   // +8 pad -> 2-way LDS conflicts only
    __shared__ int eidx[128];
    int t = threadIdx.x;
    int base = blockIdx.x * 64;
    if (t < 64)       { int e = base + t;      eidx[t] = ss[e < ESUB ? e : ESUB - 1]; }
    else if (t < 128) { int e = base + t - 64; eidx[t] = sd[e < ESUB ? e : ESUB - 1]; }
    __syncthreads();
#pragma unroll
    for (int it = 0; it < 16; it++) {
        int c = it * 256 + t;       // 0..4095
        int row = c >> 6;           // 0..63
        int cpos = c & 63;          // 16B chunk within 512-elem row
        int half = cpos >> 5;
        int off8 = (cpos & 31) * 8;
        int node = eidx[half * 64 + row];
        uint4 v = *(const uint4*)(x3b + (size_t)node * 256 + off8);
        *(uint4*)&At[row][half * 256 + off8] = v;
    }
    __syncthreads();
    int wave = t >> 6, lane = t & 63;
    int q = lane >> 4, r16 = lane & 15;
    f32x4 acc[4][4] = {};
    for (int ks = 0; ks < 16; ks++) {
        bf16x8 a[4], b[4];
        int ko = ks * 32 + q * 8;
#pragma unroll
        for (int mt = 0; mt < 4; mt++)
            a[mt] = *(const bf16x8*)&At[mt * 16 + r16][ko];
#pragma unroll
        for (int i = 0; i < 4; i++) {
            int tn = wave * 4 + i;
            b[i] = *(const bf16x8*)&Wp[((size_t)(tn * 16 + ks) * 64 + lane) * 8];
        }
#pragma unroll
        for (int mt = 0; mt < 4; mt++)
#pragma unroll
            for (int i = 0; i < 4; i++)
                acc[mt][i] = __builtin_amdgcn_mfma_f32_16x16x32_bf16(a[mt], b[i], acc[mt][i], 0, 0, 0);
    }
#pragma unroll
    for (int mt = 0; mt < 4; mt++) {
#pragma unroll
        for (int i = 0; i < 4; i++) {
            int col = (wave * 4 + i) * 16 + r16;
            float bb = bfc[col];
#pragma unroll
            for (int rr = 0; rr < 4; rr++) {
                int row = base + mt * 16 + q * 4 + rr;
                if (row < ESUB)
                    out[(size_t)row * 256 + col] = acc[mt][i][rr] + bb;
            }
        }
    }
}

extern "C" void kernel_launch(void* const* d_in, const int* in_sizes, int n_in,
                              void* d_out, int out_size, void* d_ws, size_t ws_size,
                              hipStream_t stream) {
    const int* e0_type = (const int*)d_in[0];
    const int* e0_src  = (const int*)d_in[1];
    const int* e0_dst  = (const int*)d_in[2];
    const int* e1_src  = (const int*)d_in[3];
    const int* e1_dst  = (const int*)d_in[4];
    const int* e2_src  = (const int*)d_in[5];
    const int* e2_dst  = (const int*)d_in[6];
    const int* sub_src = (const int*)d_in[7];
    const int* sub_dst = (const int*)d_in[8];
    const float* rel_emb = (const float*)d_in[9];
    const float* W_out   = (const float*)d_in[10];
    const float* b_out   = (const float*)d_in[11];
    const float* W_in    = (const float*)d_in[12];
    const float* b_in    = (const float*)d_in[13];
    const float* W1      = (const float*)d_in[14];
    const float* b1      = (const float*)d_in[15];
    const float* W2      = (const float*)d_in[16];
    const float* b2v     = (const float*)d_in[17];
    const float* Wfc     = (const float*)d_in[18];
    const float* bfc     = (const float*)d_in[19];
    float* out = (float*)d_out;

    // ---- packed workspace layout (floats), peak ~229 MB ----
    float* ws = (float*)d_ws;
    size_t o = 0;
    float* deg0_src = ws + o; o += N1;
    float* deg0_dst = ws + o; o += N1;
    float* deg1_o   = ws + o; o += N1;
    float* deg1_i   = ws + o; o += N2;
    float* deg2_o   = ws + o; o += N2;
    float* deg2_i   = ws + o; o += N3;
    size_t P0 = o;                                  // 790000
    float*  S_out = ws + P0;                        // [scatter0, combine)  N1*32
    float*  S_in  = ws + P0 + (size_t)N1 * 32;
    float*  h1    = ws + P0 + (size_t)N1 * 64;      // [combine, scatter1)  N1*64
    float*  agg1  = ws + P0;                        // [scatter1, conv1)    N2*64
    float*  agg2  = ws + P0;                        // [scatter2, conv2)    N3*256
    float*  h2    = ws + P0 + (size_t)N3 * 256;     // [conv1, scatter2)    N2*256
    __bf16* x3b   = (__bf16*)h2;                    // [conv2, end)  N3*256 bf16 (h2 dead)
    float*  tail  = ws + P0 + (size_t)N3 * 256 + (size_t)N2 * 256;
    __bf16* Wfcp  = (__bf16*)tail;                  // 512*256 bf16 = 256 KB
    __bf16* W2p   = (__bf16*)(tail + 65536);        // 256*256 bf16 = 128 KB

    const int BT = 256;

    // zero degrees + S_out/S_in
    hipMemsetAsync(ws, 0, (P0 + (size_t)N1 * 64) * sizeof(float), stream);

    // pack weights for MFMA (no dependencies on memset region)
    k_pack<<<512, BT, 0, stream>>>(Wfc, Wfcp, 16);
    k_pack<<<256, BT, 0, stream>>>(W2, W2p, 8);

    // degrees
    k_degree<<<(E0 + BT - 1) / BT, BT, 0, stream>>>(e0_src, E0, deg0_src, N1);
    k_degree<<<(E0 + BT - 1) / BT, BT, 0, stream>>>(e0_dst, E0, deg0_dst, N1);
    k_degree<<<(E1 + BT - 1) / BT, BT, 0, stream>>>(e1_src, E1, deg1_o, N1);
    k_degree<<<(E1 + BT - 1) / BT, BT, 0, stream>>>(e1_dst, E1, deg1_i, N2);
    k_degree<<<(E2 + BT - 1) / BT, BT, 0, stream>>>(e2_src, E2, deg2_o, N2);
    k_degree<<<(E2 + BT - 1) / BT, BT, 0, stream>>>(e2_dst, E2, deg2_i, N3);

    // layer 0 scatter + combine
    long long t0 = (long long)E0 * 32;
    k_scatter0<<<(int)((t0 + BT - 1) / BT), BT, 0, stream>>>(e0_type, e0_src, e0_dst, rel_emb, S_out, S_in);
    k_combine<<<(N1 * 64 + BT - 1) / BT, BT, 0, stream>>>(S_out, S_in, deg0_src, deg0_dst, deg1_o,
                                                          W_out, b_out, W_in, b_in, h1);

    // conv1
    hipMemsetAsync(agg1, 0, (size_t)N2 * 64 * sizeof(float), stream);
    long long t1 = (long long)E1 * 64;
    k_scatter1<<<(int)((t1 + BT - 1) / BT), BT, 0, stream>>>(e1_src, e1_dst, h1, agg1);
    k_conv1<<<N2 / 8, BT, 0, stream>>>(agg1, deg1_i, deg2_o, W1, b1, h2);

    // conv2 (MFMA)
    hipMemsetAsync(agg2, 0, (size_t)N3 * 256 * sizeof(float), stream);
    long long t2 = (long long)E2 * 256;
    k_scatter2<<<(int)((t2 + BT - 1) / BT), BT, 0, stream>>>(e2_src, e2_dst, h2, agg2);
    k_conv2_mfma<<<(N3 + 63) / 64, BT, 0, stream>>>(agg2, deg2_i, W2p, b2v, x3b);

    // final edge MLP (MFMA)
    k_final_mfma<<<(ESUB + 63) / 64, BT, 0, stream>>>(sub_src, sub_dst, x3b, Wfcp, bfc, out);
}